// Round 9
// baseline (463.845 us; speedup 1.0000x reference)
//
#include <hip/hip_runtime.h>
#include <stdint.h>

// Problem constants (fixed by the reference)
#define NN 50000
#define EE 800000
#define FF 256
#define HH 256
#define LL 128
#define SBLK 1024   // bnstats stage-A blocks (4/CU -> 16 waves/CU latency hiding)

typedef __bf16 bf16x8 __attribute__((ext_vector_type(8)));
typedef float  f32x4  __attribute__((ext_vector_type(4)));

typedef __attribute__((address_space(1))) unsigned int uint_as1;
typedef __attribute__((address_space(3))) unsigned int uint_as3;

__device__ __forceinline__ unsigned short f2bf(float f) {
  union { float f; unsigned int u; } v; v.f = f;
  unsigned int u = v.u;
  u += 0x7FFFu + ((u >> 16) & 1u);   // RTNE (finite inputs only)
  return (unsigned short)(u >> 16);
}

__device__ __forceinline__ float bf2f(unsigned short u) {
  union { unsigned int u; float f; } v;
  v.u = ((unsigned int)u) << 16;
  return v.f;
}

__device__ __forceinline__ f32x4 bf4_to_f32(ushort4 u) {
  f32x4 r;
  r.x = bf2f(u.x); r.y = bf2f(u.y); r.z = bf2f(u.z); r.w = bf2f(u.w);
  return r;
}

__device__ __forceinline__ void gload_lds16(const void* g, void* l) {
  __builtin_amdgcn_global_load_lds((const uint_as1*)g, (uint_as3*)l, 16, 0, 0);
}

// ---------------- fused setup: features cast + LDS-tiled weight transposes + zeroing ----
// grid: [0,12500) features | [12500,12516) W1 | [12516,12532) W2 | [12532,12540) Wf
//       [12540,12589) zero cnt | 12589 zero stats
__global__ __launch_bounds__(256) void k_casts(const float* __restrict__ features,
                                               unsigned short* __restrict__ Xb,
                                               const float* __restrict__ W1,
                                               unsigned short* __restrict__ W1t,
                                               const float* __restrict__ W2,
                                               unsigned short* __restrict__ W2t,
                                               const float* __restrict__ Wf,
                                               unsigned short* __restrict__ Wft,
                                               int* __restrict__ cnt,
                                               int* __restrict__ statz) {
  __shared__ float tl[64 * 65];
  int b = blockIdx.x, t = threadIdx.x;
  if (b < 12500) {
    int i = b * 256 + t;  // n4 = 3,200,000 exactly
    f32x4 x = ((const f32x4*)features)[i];
    ushort4 o;
    o.x = f2bf(x.x); o.y = f2bf(x.y); o.z = f2bf(x.z); o.w = f2bf(x.w);
    ((ushort4*)Xb)[i] = o;
  } else if (b < 12540) {
    const float* in;
    unsigned short* out;
    int Nin, k0, n0;
    if (b < 12516) {
      in = W1; out = W1t; Nin = HH;
      int tt = b - 12500; k0 = (tt >> 2) * 64; n0 = (tt & 3) * 64;
    } else if (b < 12532) {
      in = W2; out = W2t; Nin = HH;
      int tt = b - 12516; k0 = (tt >> 2) * 64; n0 = (tt & 3) * 64;
    } else {
      in = Wf; out = Wft; Nin = LL;
      int tt = b - 12532; k0 = (tt >> 1) * 64; n0 = (tt & 1) * 64;
    }
    // read 64x64 tile coalesced: tl[kr][nc] = in[(k0+kr)*Nin + n0+nc]
#pragma unroll
    for (int j = 0; j < 16; ++j) {
      int idx = j * 256 + t;
      int r = idx >> 6, c = idx & 63;
      tl[r * 65 + c] = in[(size_t)(k0 + r) * Nin + n0 + c];
    }
    __syncthreads();
    // write coalesced: out[(n0+r)*K + k0+c] = tl[c*65 + r]
#pragma unroll
    for (int j = 0; j < 16; ++j) {
      int idx = j * 256 + t;
      int r = idx >> 6, c = idx & 63;
      out[(size_t)(n0 + r) * HH + k0 + c] = f2bf(tl[c * 65 + r]);
    }
  } else if (b < 12589) {
    int base = (b - 12540) * 1024 + t * 4;
    if (base + 3 < NN) {
      int4 z = {0, 0, 0, 0};
      *(int4*)(cnt + base) = z;
    } else {
      for (int j = 0; j < 4; ++j)
        if (base + j < NN) cnt[base + j] = 0;
    }
  } else {
    for (int i = t; i < 4 * HH + 64; i += 256) statz[i] = 0;
  }
}

// ---------------- CSR build ----------------
__global__ __launch_bounds__(256) void k_hist(const int* __restrict__ rows,
                                              int* __restrict__ cnt, int E) {
  int i = blockIdx.x * 256 + threadIdx.x;
  if (i < E) atomicAdd(&cnt[rows[i]], 1);
}

// Unordered exclusive allocation: wave-scan of counts + one global atomic per wave.
__global__ __launch_bounds__(256) void k_alloc(const int* __restrict__ cnt,
                                               int* __restrict__ cursor,
                                               int* __restrict__ total, int n) {
  int i = blockIdx.x * 256 + threadIdx.x;
  int lane = threadIdx.x & 63;
  int c = (i < n) ? cnt[i] : 0;
  int incl = c;
#pragma unroll
  for (int off = 1; off < 64; off <<= 1) {
    int v = __shfl_up(incl, off, 64);
    if (lane >= off) incl += v;
  }
  int excl = incl - c;
  int wtot = __shfl(incl, 63, 64);
  int base = 0;
  if (lane == 0) base = atomicAdd(total, wtot);
  base = __shfl(base, 0, 64);
  if (i < n) cursor[i] = base + excl;
}

// CSR entry packed to 4B: (col << 16) | bf16(val). col < 50000 < 65536.
// 2 edges per thread (E is even).
__global__ __launch_bounds__(256) void k_fill(const int* __restrict__ rows,
                                              const int* __restrict__ cols,
                                              const float* __restrict__ vals,
                                              int* __restrict__ cursor,
                                              unsigned int* __restrict__ csr, int E) {
  int i = (blockIdx.x * 256 + threadIdx.x) * 2;
  if (i + 1 < E) {
    int2 r2 = *(const int2*)(rows + i);
    int2 c2 = *(const int2*)(cols + i);
    float2 v2 = *(const float2*)(vals + i);
    int p0 = atomicAdd(&cursor[r2.x], 1);
    csr[p0] = ((unsigned int)c2.x << 16) | (unsigned int)f2bf(v2.x);
    int p1 = atomicAdd(&cursor[r2.y], 1);
    csr[p1] = ((unsigned int)c2.y << 16) | (unsigned int)f2bf(v2.y);
  } else if (i < E) {
    int p = atomicAdd(&cursor[rows[i]], 1);
    csr[p] = ((unsigned int)cols[i] << 16) | (unsigned int)f2bf(vals[i]);
  }
}

// ---------------- SpMM (bf16 in / bf16 out): Y[i] = sum_e val*X[col] ----------------
// One wave per row (lane = ushort4 -> full 512B row per gather), 4 edge streams.
// After k_fill, cursor[row] == row end; start = end - cnt[row].
// At structural floor: FETCH ~175MB = 8 XCDs x ~86% of X unique-touch, L2-miss path
// ceiling ~3.7 TB/s (measured stable R1/R4/R8) -> ~56 us.
__global__ __launch_bounds__(256) void k_spmm(const unsigned short* __restrict__ X,
                                              const int* __restrict__ endp,
                                              const int* __restrict__ cnt,
                                              const unsigned int* __restrict__ csr,
                                              unsigned short* __restrict__ Y, int n) {
  int row = blockIdx.x * 4 + (threadIdx.x >> 6);
  int lane = threadIdx.x & 63;
  if (row >= n) return;
  int e = endp[row];
  int s = e - cnt[row];
  f32x4 a0 = {0.f, 0.f, 0.f, 0.f};
  f32x4 a1 = a0, a2 = a0, a3 = a0;
  int p = s;
  int e4 = s + ((e - s) & ~3);
  for (; p < e4; p += 4) {
    unsigned int c0 = csr[p + 0], c1 = csr[p + 1], c2 = csr[p + 2], c3 = csr[p + 3];
    ushort4 x0 = ((const ushort4*)(X + (size_t)(c0 >> 16) * HH))[lane];
    ushort4 x1 = ((const ushort4*)(X + (size_t)(c1 >> 16) * HH))[lane];
    ushort4 x2 = ((const ushort4*)(X + (size_t)(c2 >> 16) * HH))[lane];
    ushort4 x3 = ((const ushort4*)(X + (size_t)(c3 >> 16) * HH))[lane];
    a0 += bf2f((unsigned short)c0) * bf4_to_f32(x0);
    a1 += bf2f((unsigned short)c1) * bf4_to_f32(x1);
    a2 += bf2f((unsigned short)c2) * bf4_to_f32(x2);
    a3 += bf2f((unsigned short)c3) * bf4_to_f32(x3);
  }
  for (; p < e; ++p) {
    unsigned int c0 = csr[p];
    ushort4 x0 = ((const ushort4*)(X + (size_t)(c0 >> 16) * HH))[lane];
    a0 += bf2f((unsigned short)c0) * bf4_to_f32(x0);
  }
  f32x4 a = (a0 + a1) + (a2 + a3);
  ushort4 o;
  o.x = f2bf(a.x); o.y = f2bf(a.y); o.z = f2bf(a.z); o.w = f2bf(a.w);
  ((ushort4*)(Y + (size_t)row * HH))[lane] = o;
}

// ---------------- BatchNorm stats, two-stage (atomic-light) ----------------
// Stage A: SBLK blocks (4/CU); wave-per-4-rows ushort4 loads; LDS reduce (pad 9);
// block writes 512 partials contiguously. part layout: [stat(2)][SBLK][256]
__global__ __launch_bounds__(256) void k_bnstats(const unsigned short* __restrict__ X,
                                                 float* __restrict__ part, int n) {
  __shared__ float red[4][64][9];
  const int w = threadIdx.x >> 6, l = threadIdx.x & 63;
  f32x4 s = {0.f, 0.f, 0.f, 0.f}, s2 = {0.f, 0.f, 0.f, 0.f};
  for (int r = blockIdx.x * 4 + w; r < n; r += gridDim.x * 4) {
    f32x4 v = bf4_to_f32(((const ushort4*)(X + (size_t)r * HH))[l]);
    s += v;
    s2 += v * v;
  }
#pragma unroll
  for (int j = 0; j < 4; ++j) { red[w][l][j] = s[j]; red[w][l][4 + j] = s2[j]; }
  __syncthreads();
  if (threadIdx.x < 64) {
    int ll = threadIdx.x;
#pragma unroll
    for (int j = 0; j < 8; ++j) {
      float v = red[0][ll][j] + red[1][ll][j] + red[2][ll][j] + red[3][ll][j];
      int c = ll * 4 + (j & 3);
      part[((j < 4) ? 0 : (SBLK * 256)) + blockIdx.x * 256 + c] = v;
    }
  }
}

// Stage B: 16 blocks = 8 chunks x 2 stats; 128 partials each, 8-deep atomicAdd/col.
__global__ __launch_bounds__(256) void k_bnred(const float* __restrict__ part,
                                               float* __restrict__ sums) {
  int c = threadIdx.x;
  int stat = blockIdx.x >> 3, chunk = blockIdx.x & 7;
  const float* p = part + stat * (SBLK * 256) + chunk * 128 * 256;
  float s0 = 0.f, s1 = 0.f, s2 = 0.f, s3 = 0.f;
  for (int b = 0; b < 128; b += 4) {
    s0 += p[(b + 0) * 256 + c];
    s1 += p[(b + 1) * 256 + c];
    s2 += p[(b + 2) * 256 + c];
    s3 += p[(b + 3) * 256 + c];
  }
  atomicAdd(&sums[stat * HH + c], (s0 + s1) + (s2 + s3));
}

// y = bf16(relu(x*scale + shift)); scale/shift computed per-block from raw sums
__global__ __launch_bounds__(256) void k_bnrc(const unsigned short* __restrict__ X,
                                              const float* __restrict__ sums,
                                              const float* __restrict__ g,
                                              const float* __restrict__ be,
                                              unsigned short* __restrict__ out, int n4) {
  __shared__ float sc[HH], sh[HH];
  int t = threadIdx.x;
  {
    float inv = 1.f / (float)NN;
    float mean = sums[t] * inv;
    float var = sums[HH + t] * inv - mean * mean;
    float s = g[t] * rsqrtf(var + 1e-5f);
    sc[t] = s;
    sh[t] = be[t] - mean * s;
  }
  __syncthreads();
  for (int i = blockIdx.x * 256 + t; i < n4; i += gridDim.x * 256) {
    f32x4 x = bf4_to_f32(((const ushort4*)X)[i]);
    int c0 = (i * 4) & (HH - 1);
    ushort4 o;
    o.x = f2bf(fmaxf(x.x * sc[c0 + 0] + sh[c0 + 0], 0.f));
    o.y = f2bf(fmaxf(x.y * sc[c0 + 1] + sh[c0 + 1], 0.f));
    o.z = f2bf(fmaxf(x.z * sc[c0 + 2] + sh[c0 + 2], 0.f));
    o.w = f2bf(fmaxf(x.w * sc[c0 + 3] + sh[c0 + 3], 0.f));
    ((ushort4*)out)[i] = o;
  }
}

// Layer-2 BN apply, packed for the head: out[r] = bf16(relu(BN(X[idx[r]]))).
// Wave-uniform idx row per 64-lane group -> coalesced 512B row reads.
// grid = nrow*64/256 blocks exactly (25000*64 = 1.6M quads).
__global__ __launch_bounds__(256) void k_bnrc_pack(const unsigned short* __restrict__ X,
                                                   const float* __restrict__ sums,
                                                   const float* __restrict__ g,
                                                   const float* __restrict__ be,
                                                   const int* __restrict__ idx,
                                                   unsigned short* __restrict__ out) {
  __shared__ float sc[HH], sh[HH];
  int t = threadIdx.x;
  {
    float inv = 1.f / (float)NN;
    float mean = sums[t] * inv;
    float var = sums[HH + t] * inv - mean * mean;
    float s = g[t] * rsqrtf(var + 1e-5f);
    sc[t] = s;
    sh[t] = be[t] - mean * s;
  }
  __syncthreads();
  int i = blockIdx.x * 256 + t;
  int orow = i >> 6;           // wave-uniform
  int c0 = (i & 63) * 4;
  int irow = idx[orow];
  f32x4 x = bf4_to_f32(*(const ushort4*)(X + (size_t)irow * HH + c0));
  ushort4 o;
  o.x = f2bf(fmaxf(x.x * sc[c0 + 0] + sh[c0 + 0], 0.f));
  o.y = f2bf(fmaxf(x.y * sc[c0 + 1] + sh[c0 + 1], 0.f));
  o.z = f2bf(fmaxf(x.z * sc[c0 + 2] + sh[c0 + 2], 0.f));
  o.w = f2bf(fmaxf(x.w * sc[c0 + 3] + sh[c0 + 3], 0.f));
  ((ushort4*)out)[i] = o;
}

// ---------------- GEMM: C(MxNn) = A(MxK,bf16) * Bt(NnxK,bf16)^T + bias ----------------
// 128x128 tile, BK=64, 4 waves (2x2), each wave 4x4 grid of 16x16x32 MFMAs x 2
// k-substeps. 3 blocks/CU (48KB LDS x3 = 144 <= 160KB): 782 blocks -> ~1.02 rounds
// instead of 1.53 at 2/CU. OUTB=1: bf16 out; 0: fp32 out.
template <int OUTB>
__global__ __launch_bounds__(256, 3) void k_gemm(const unsigned short* __restrict__ A,
                                                 const unsigned short* __restrict__ Bt,
                                                 const float* __restrict__ bias,
                                                 void* __restrict__ Cv,
                                                 int M, int K, int Nn) {
  __shared__ unsigned short lA[128 * 64];  // 16 KB, rows of 128B
  __shared__ unsigned short lB[128 * 64];  // 16 KB
  const int tid = threadIdx.x;
  const int wave = tid >> 6, lane = tid & 63;
  const int m0 = blockIdx.x * 128, n0 = blockIdx.y * 128;
  const int wm = (wave >> 1) * 64, wn = (wave & 1) * 64;
  const int lhi = lane >> 4, llo = lane & 15;

  // staging: 4 issues per wave per operand; issue j covers 8 rows x 64 cols
  // (128B rows, 8 lanes/row, 16B/lane)
  const int srow = lane >> 3;        // 0..7
  const int scol = (lane & 7) * 8;   // elem offset
  const unsigned short *pA[4], *pB[4];
#pragma unroll
  for (int j = 0; j < 4; ++j) {
    int base = (wave * 4 + j) * 8 + srow;
    int ar = m0 + base;
    ar = ar < M ? ar : 0;
    pA[j] = A + (size_t)ar * K + scol;
    pB[j] = Bt + (size_t)(n0 + base) * K + scol;
  }

  f32x4 zero = {0.f, 0.f, 0.f, 0.f};
  f32x4 acc[4][4];
#pragma unroll
  for (int i = 0; i < 4; ++i)
#pragma unroll
    for (int j = 0; j < 4; ++j) acc[i][j] = zero;

  for (int k0 = 0; k0 < K; k0 += 64) {
#pragma unroll
    for (int j = 0; j < 4; ++j) {
      gload_lds16(pA[j] + k0, lA + (wave * 4 + j) * 8 * 64);
      gload_lds16(pB[j] + k0, lB + (wave * 4 + j) * 8 * 64);
    }
    __syncthreads();  // drains vmcnt -> LDS valid
    bf16x8 af[2][4], bfv[2][4];
#pragma unroll
    for (int ks = 0; ks < 2; ++ks) {
#pragma unroll
      for (int mt = 0; mt < 4; ++mt)
        af[ks][mt] = *(const bf16x8*)(lA + (wm + mt * 16 + llo) * 64 + ks * 32 + lhi * 8);
#pragma unroll
      for (int nt = 0; nt < 4; ++nt)
        bfv[ks][nt] = *(const bf16x8*)(lB + (wn + nt * 16 + llo) * 64 + ks * 32 + lhi * 8);
    }
#pragma unroll
    for (int ks = 0; ks < 2; ++ks)
#pragma unroll
      for (int mt = 0; mt < 4; ++mt)
#pragma unroll
        for (int nt = 0; nt < 4; ++nt)
          acc[mt][nt] = __builtin_amdgcn_mfma_f32_16x16x32_bf16(af[ks][mt], bfv[ks][nt], acc[mt][nt], 0, 0, 0);
    __syncthreads();  // all reads done before next stage
  }

#pragma unroll
  for (int nt = 0; nt < 4; ++nt) {
    int cn = n0 + wn + nt * 16 + llo;
    float bv = bias ? bias[cn] : 0.f;
#pragma unroll
    for (int mt = 0; mt < 4; ++mt) {
      int cm0 = m0 + wm + mt * 16 + lhi * 4;
#pragma unroll
      for (int r = 0; r < 4; ++r) {
        int cm = cm0 + r;
        if (cm < M) {
          float v = acc[mt][nt][r] + bv;
          if (OUTB)
            ((unsigned short*)Cv)[(size_t)cm * Nn + cn] = f2bf(v);
          else
            ((float*)Cv)[(size_t)cm * Nn + cn] = v;
        }
      }
    }
  }
}

extern "C" void kernel_launch(void* const* d_in, const int* in_sizes, int n_in,
                              void* d_out, int out_size, void* d_ws, size_t ws_size,
                              hipStream_t stream) {
  const float* features = (const float*)d_in[0];
  const float* edge_vals = (const float*)d_in[1];
  const float* W1 = (const float*)d_in[2];
  const float* db1 = (const float*)d_in[3];
  // d_in[4] = b1  — annihilated by training-mode BN (constant per column before mean-subtract)
  const float* g1 = (const float*)d_in[5];
  const float* be1 = (const float*)d_in[6];
  const float* W2 = (const float*)d_in[7];
  // d_in[8] = b2  — annihilated by BN
  const float* g2 = (const float*)d_in[9];
  const float* be2 = (const float*)d_in[10];
  const float* Wf = (const float*)d_in[11];
  const float* bfb = (const float*)d_in[12];
  const int* erows = (const int*)d_in[13];
  const int* ecols = (const int*)d_in[14];
  const int* idx = (const int*)d_in[15];
  const int M3 = in_sizes[15];
  (void)n_in; (void)out_size; (void)ws_size;

  char* ws = (char*)d_ws;
  size_t off = 0;
  auto alloc = [&](size_t bytes) -> void* {
    void* p = (void*)(ws + off);
    off += (bytes + 255) & ~(size_t)255;
    return p;
  };
  unsigned short* Xb = (unsigned short*)alloc((size_t)NN * HH * 2);  // features / hidden (bf16)
  unsigned short* Ab = (unsigned short*)alloc((size_t)NN * HH * 2);  // gemm out (bf16)
  unsigned short* Yb = (unsigned short*)alloc((size_t)NN * HH * 2);  // spmm out (bf16)
  unsigned short* Pb = (unsigned short*)alloc((size_t)25000 * HH * 2);  // packed head A
  unsigned short* W1t = (unsigned short*)alloc((size_t)FF * HH * 2);
  unsigned short* W2t = (unsigned short*)alloc((size_t)HH * HH * 2);
  unsigned short* Wft = (unsigned short*)alloc((size_t)HH * LL * 2);
  int* cursor = (int*)alloc((size_t)NN * 4);
  int* cnt = (int*)alloc((size_t)NN * 4);
  unsigned int* csr = (unsigned int*)alloc((size_t)EE * 4);
  float* part = (float*)alloc((size_t)2 * SBLK * 256 * 4);  // bn partials (2 MB)
  float* stats = (float*)alloc(4 * HH * 4 + 256);  // sums1|sums2|total
  float* sums1 = stats;
  float* sums2 = stats + 2 * HH;
  int* total = (int*)(stats + 4 * HH);

  // all dtype conversions + workspace zeroing in one launch
  k_casts<<<12590, 256, 0, stream>>>(features, Xb, W1, W1t, W2, W2t, Wf, Wft,
                                     cnt, (int*)stats);

  // CSR build (reused by both SpMMs); row bases via unordered atomic allocation
  k_hist<<<(EE + 255) / 256, 256, 0, stream>>>(erows, cnt, EE);
  k_alloc<<<(NN + 255) / 256, 256, 0, stream>>>(cnt, cursor, total, NN);
  k_fill<<<(EE / 2 + 255) / 256, 256, 0, stream>>>(erows, ecols, edge_vals, cursor, csr, EE);
  // after k_fill: cursor[row] == row end

  // layer 1
  k_gemm<1><<<dim3((NN + 127) / 128, HH / 128), 256, 0, stream>>>(Xb, W1t, db1, Ab, NN, FF, HH);
  k_spmm<<<(NN + 3) / 4, 256, 0, stream>>>(Ab, cursor, cnt, csr, Yb, NN);
  k_bnstats<<<SBLK, 256, 0, stream>>>(Yb, part, NN);
  k_bnred<<<16, 256, 0, stream>>>(part, sums1);
  k_bnrc<<<2048, 256, 0, stream>>>(Yb, sums1, g1, be1, Xb, NN * HH / 4);

  // layer 2
  k_gemm<1><<<dim3((NN + 127) / 128, HH / 128), 256, 0, stream>>>(Xb, W2t, nullptr, Ab, NN, HH, HH);
  k_spmm<<<(NN + 3) / 4, 256, 0, stream>>>(Ab, cursor, cnt, csr, Yb, NN);
  k_bnstats<<<SBLK, 256, 0, stream>>>(Yb, part, NN);
  k_bnred<<<16, 256, 0, stream>>>(part, sums2);
  // BN apply only for the 25000 head rows, packed (idx gather folded in here)
  k_bnrc_pack<<<(M3 * 64) / 256, 256, 0, stream>>>(Yb, sums2, g2, be2, idx, Pb);

  // head: C = Pb @ Wf + bf (rows already gathered+BN'd)
  k_gemm<0><<<dim3((M3 + 127) / 128, LL / 128), 256, 0, stream>>>(Pb, Wft, bfb, d_out, M3, HH, LL);
}

// Round 10
// 433.837 us; speedup vs baseline: 1.0692x; 1.0692x over previous
//
#include <hip/hip_runtime.h>
#include <stdint.h>

// Problem constants (fixed by the reference)
#define NN 50000
#define EE 800000
#define FF 256
#define HH 256
#define LL 128
#define SBLK 1024   // bnstats stage-A blocks

typedef __bf16 bf16x8 __attribute__((ext_vector_type(8)));
typedef float  f32x4  __attribute__((ext_vector_type(4)));

typedef __attribute__((address_space(1))) unsigned int uint_as1;
typedef __attribute__((address_space(3))) unsigned int uint_as3;

__device__ __forceinline__ unsigned short f2bf(float f) {
  union { float f; unsigned int u; } v; v.f = f;
  unsigned int u = v.u;
  u += 0x7FFFu + ((u >> 16) & 1u);   // RTNE (finite inputs only)
  return (unsigned short)(u >> 16);
}

__device__ __forceinline__ float bf2f(unsigned short u) {
  union { unsigned int u; float f; } v;
  v.u = ((unsigned int)u) << 16;
  return v.f;
}

__device__ __forceinline__ f32x4 bf4_to_f32(ushort4 u) {
  f32x4 r;
  r.x = bf2f(u.x); r.y = bf2f(u.y); r.z = bf2f(u.z); r.w = bf2f(u.w);
  return r;
}

__device__ __forceinline__ void gload_lds16(const void* g, void* l) {
  __builtin_amdgcn_global_load_lds((const uint_as1*)g, (uint_as3*)l, 16, 0, 0);
}

// ---------------- fused setup: edge histogram + feature cast + weight transposes ----
// grid: [0,3125) hist | [3125,15625) features | [15625,15665) weight 64x64 tiles
// hist first so its latency-bound atomic waves overlap the streaming casts.
__global__ __launch_bounds__(256) void k_setup(const int* __restrict__ erows,
                                               int* __restrict__ cnt,
                                               const float* __restrict__ features,
                                               unsigned short* __restrict__ Xb,
                                               const float* __restrict__ W1,
                                               unsigned short* __restrict__ W1t,
                                               const float* __restrict__ W2,
                                               unsigned short* __restrict__ W2t,
                                               const float* __restrict__ Wf,
                                               unsigned short* __restrict__ Wft) {
  __shared__ float tl[64 * 65];
  int b = blockIdx.x, t = threadIdx.x;
  if (b < 3125) {
    int i = b * 256 + t;
    if (i < EE) atomicAdd(&cnt[erows[i]], 1);
  } else if (b < 15625) {
    int i = (b - 3125) * 256 + t;  // n4 = 3,200,000 exactly
    f32x4 x = ((const f32x4*)features)[i];
    ushort4 o;
    o.x = f2bf(x.x); o.y = f2bf(x.y); o.z = f2bf(x.z); o.w = f2bf(x.w);
    ((ushort4*)Xb)[i] = o;
  } else {
    int tt = b - 15625;
    const float* in;
    unsigned short* out;
    int Nin, k0, n0;
    if (tt < 16) {
      in = W1; out = W1t; Nin = HH;
      k0 = (tt >> 2) * 64; n0 = (tt & 3) * 64;
    } else if (tt < 32) {
      in = W2; out = W2t; Nin = HH;
      tt -= 16; k0 = (tt >> 2) * 64; n0 = (tt & 3) * 64;
    } else {
      in = Wf; out = Wft; Nin = LL;
      tt -= 32; k0 = (tt >> 1) * 64; n0 = (tt & 1) * 64;
    }
#pragma unroll
    for (int j = 0; j < 16; ++j) {
      int idx = j * 256 + t;
      int r = idx >> 6, c = idx & 63;
      tl[r * 65 + c] = in[(size_t)(k0 + r) * Nin + n0 + c];
    }
    __syncthreads();
#pragma unroll
    for (int j = 0; j < 16; ++j) {
      int idx = j * 256 + t;
      int r = idx >> 6, c = idx & 63;
      out[(size_t)(n0 + r) * HH + k0 + c] = f2bf(tl[c * 65 + r]);
    }
  }
}

// Unordered exclusive allocation: wave-scan of counts + one global atomic per wave.
__global__ __launch_bounds__(256) void k_alloc(const int* __restrict__ cnt,
                                               int* __restrict__ cursor,
                                               int* __restrict__ total, int n) {
  int i = blockIdx.x * 256 + threadIdx.x;
  int lane = threadIdx.x & 63;
  int c = (i < n) ? cnt[i] : 0;
  int incl = c;
#pragma unroll
  for (int off = 1; off < 64; off <<= 1) {
    int v = __shfl_up(incl, off, 64);
    if (lane >= off) incl += v;
  }
  int excl = incl - c;
  int wtot = __shfl(incl, 63, 64);
  int base = 0;
  if (lane == 0) base = atomicAdd(total, wtot);
  base = __shfl(base, 0, 64);
  if (i < n) cursor[i] = base + excl;
}

// ---------------- fused layer-1 GEMM + CSR fill ----------------
// 1564 blocks: even = gemm tile (gb = b>>1, 782 tiles of 128x128), odd = fill
// (grid-stride, 4 independent atomic+scatter per thread). Fill's atomic latency
// hides under gemm's MFMA work (separate pipes co-schedule).
// CSR entry packed to 4B: (col << 16) | bf16(val).
__global__ __launch_bounds__(256, 3) void k_l1(const unsigned short* __restrict__ A,
                                               const unsigned short* __restrict__ Bt,
                                               const float* __restrict__ bias,
                                               unsigned short* __restrict__ C,
                                               int M, int K, int Nn,
                                               const int* __restrict__ rows,
                                               const int* __restrict__ cols,
                                               const float* __restrict__ vals,
                                               int* __restrict__ cursor,
                                               unsigned int* __restrict__ csr, int E) {
  __shared__ unsigned short lA[128 * 64];  // 16 KB
  __shared__ unsigned short lB[128 * 64];  // 16 KB
  const int b = blockIdx.x;
  const int tid = threadIdx.x;
  if (b & 1) {
    for (int i = (b >> 1) * 256 + tid; i < E; i += 782 * 256) {
      int p = atomicAdd(&cursor[rows[i]], 1);
      csr[p] = ((unsigned int)cols[i] << 16) | (unsigned int)f2bf(vals[i]);
    }
    return;
  }
  const int gb = b >> 1;
  const int m0 = (gb % 391) * 128, n0 = (gb / 391) * 128;
  const int wave = tid >> 6, lane = tid & 63;
  const int wm = (wave >> 1) * 64, wn = (wave & 1) * 64;
  const int lhi = lane >> 4, llo = lane & 15;
  const int srow = lane >> 3;
  const int scol = (lane & 7) * 8;
  const unsigned short *pA[4], *pB[4];
#pragma unroll
  for (int j = 0; j < 4; ++j) {
    int base = (wave * 4 + j) * 8 + srow;
    int ar = m0 + base;
    ar = ar < M ? ar : 0;
    pA[j] = A + (size_t)ar * K + scol;
    pB[j] = Bt + (size_t)(n0 + base) * K + scol;
  }
  f32x4 zero = {0.f, 0.f, 0.f, 0.f};
  f32x4 acc[4][4];
#pragma unroll
  for (int i = 0; i < 4; ++i)
#pragma unroll
    for (int j = 0; j < 4; ++j) acc[i][j] = zero;
  for (int k0 = 0; k0 < K; k0 += 64) {
#pragma unroll
    for (int j = 0; j < 4; ++j) {
      gload_lds16(pA[j] + k0, lA + (wave * 4 + j) * 8 * 64);
      gload_lds16(pB[j] + k0, lB + (wave * 4 + j) * 8 * 64);
    }
    __syncthreads();
    bf16x8 af[2][4], bfv[2][4];
#pragma unroll
    for (int ks = 0; ks < 2; ++ks) {
#pragma unroll
      for (int mt = 0; mt < 4; ++mt)
        af[ks][mt] = *(const bf16x8*)(lA + (wm + mt * 16 + llo) * 64 + ks * 32 + lhi * 8);
#pragma unroll
      for (int nt = 0; nt < 4; ++nt)
        bfv[ks][nt] = *(const bf16x8*)(lB + (wn + nt * 16 + llo) * 64 + ks * 32 + lhi * 8);
    }
#pragma unroll
    for (int ks = 0; ks < 2; ++ks)
#pragma unroll
      for (int mt = 0; mt < 4; ++mt)
#pragma unroll
        for (int nt = 0; nt < 4; ++nt)
          acc[mt][nt] = __builtin_amdgcn_mfma_f32_16x16x32_bf16(af[ks][mt], bfv[ks][nt], acc[mt][nt], 0, 0, 0);
    __syncthreads();
  }
#pragma unroll
  for (int nt = 0; nt < 4; ++nt) {
    int cn = n0 + wn + nt * 16 + llo;
    float bv = bias[cn];
#pragma unroll
    for (int mt = 0; mt < 4; ++mt) {
      int cm0 = m0 + wm + mt * 16 + lhi * 4;
#pragma unroll
      for (int r = 0; r < 4; ++r) {
        int cm = cm0 + r;
        if (cm < M) C[(size_t)cm * Nn + cn] = f2bf(acc[mt][nt][r] + bv);
      }
    }
  }
}

// ---------------- SpMM (bf16 in / bf16 out): Y[i] = sum_e val*X[col] ----------------
// One wave per row (lane = ushort4 -> full 512B row per gather), 4 edge streams.
// After fill, cursor[row] == row end; start = end - cnt[row].
// Structural floor: FETCH ~175MB = 8 XCDs x ~86% unique-touch of X; ~3.7 TB/s
// L2-miss path -> ~56 us (measured stable R4/R8).
__global__ __launch_bounds__(256) void k_spmm(const unsigned short* __restrict__ X,
                                              const int* __restrict__ endp,
                                              const int* __restrict__ cnt,
                                              const unsigned int* __restrict__ csr,
                                              unsigned short* __restrict__ Y, int n) {
  int row = blockIdx.x * 4 + (threadIdx.x >> 6);
  int lane = threadIdx.x & 63;
  if (row >= n) return;
  int e = endp[row];
  int s = e - cnt[row];
  f32x4 a0 = {0.f, 0.f, 0.f, 0.f};
  f32x4 a1 = a0, a2 = a0, a3 = a0;
  int p = s;
  int e4 = s + ((e - s) & ~3);
  for (; p < e4; p += 4) {
    unsigned int c0 = csr[p + 0], c1 = csr[p + 1], c2 = csr[p + 2], c3 = csr[p + 3];
    ushort4 x0 = ((const ushort4*)(X + (size_t)(c0 >> 16) * HH))[lane];
    ushort4 x1 = ((const ushort4*)(X + (size_t)(c1 >> 16) * HH))[lane];
    ushort4 x2 = ((const ushort4*)(X + (size_t)(c2 >> 16) * HH))[lane];
    ushort4 x3 = ((const ushort4*)(X + (size_t)(c3 >> 16) * HH))[lane];
    a0 += bf2f((unsigned short)c0) * bf4_to_f32(x0);
    a1 += bf2f((unsigned short)c1) * bf4_to_f32(x1);
    a2 += bf2f((unsigned short)c2) * bf4_to_f32(x2);
    a3 += bf2f((unsigned short)c3) * bf4_to_f32(x3);
  }
  for (; p < e; ++p) {
    unsigned int c0 = csr[p];
    ushort4 x0 = ((const ushort4*)(X + (size_t)(c0 >> 16) * HH))[lane];
    a0 += bf2f((unsigned short)c0) * bf4_to_f32(x0);
  }
  f32x4 a = (a0 + a1) + (a2 + a3);
  ushort4 o;
  o.x = f2bf(a.x); o.y = f2bf(a.y); o.z = f2bf(a.z); o.w = f2bf(a.w);
  ((ushort4*)(Y + (size_t)row * HH))[lane] = o;
}

// ---------------- BatchNorm stats, two-stage (atomic-light) ----------------
__global__ __launch_bounds__(256) void k_bnstats(const unsigned short* __restrict__ X,
                                                 float* __restrict__ part, int n) {
  __shared__ float red[4][64][9];
  const int w = threadIdx.x >> 6, l = threadIdx.x & 63;
  f32x4 s = {0.f, 0.f, 0.f, 0.f}, s2 = {0.f, 0.f, 0.f, 0.f};
  for (int r = blockIdx.x * 4 + w; r < n; r += gridDim.x * 4) {
    f32x4 v = bf4_to_f32(((const ushort4*)(X + (size_t)r * HH))[l]);
    s += v;
    s2 += v * v;
  }
#pragma unroll
  for (int j = 0; j < 4; ++j) { red[w][l][j] = s[j]; red[w][l][4 + j] = s2[j]; }
  __syncthreads();
  if (threadIdx.x < 64) {
    int ll = threadIdx.x;
#pragma unroll
    for (int j = 0; j < 8; ++j) {
      float v = red[0][ll][j] + red[1][ll][j] + red[2][ll][j] + red[3][ll][j];
      int c = ll * 4 + (j & 3);
      part[((j < 4) ? 0 : (SBLK * 256)) + blockIdx.x * 256 + c] = v;
    }
  }
}

// Stage B: 16 blocks = 8 chunks x 2 stats; 128 partials each, 8-deep atomicAdd/col.
__global__ __launch_bounds__(256) void k_bnred(const float* __restrict__ part,
                                               float* __restrict__ sums) {
  int c = threadIdx.x;
  int stat = blockIdx.x >> 3, chunk = blockIdx.x & 7;
  const float* p = part + stat * (SBLK * 256) + chunk * 128 * 256;
  float s0 = 0.f, s1 = 0.f, s2 = 0.f, s3 = 0.f;
  for (int b = 0; b < 128; b += 4) {
    s0 += p[(b + 0) * 256 + c];
    s1 += p[(b + 1) * 256 + c];
    s2 += p[(b + 2) * 256 + c];
    s3 += p[(b + 3) * 256 + c];
  }
  atomicAdd(&sums[stat * HH + c], (s0 + s1) + (s2 + s3));
}

// y = bf16(relu(x*scale + shift)); scale/shift computed per-block from raw sums
__global__ __launch_bounds__(256) void k_bnrc(const unsigned short* __restrict__ X,
                                              const float* __restrict__ sums,
                                              const float* __restrict__ g,
                                              const float* __restrict__ be,
                                              unsigned short* __restrict__ out, int n4) {
  __shared__ float sc[HH], sh[HH];
  int t = threadIdx.x;
  {
    float inv = 1.f / (float)NN;
    float mean = sums[t] * inv;
    float var = sums[HH + t] * inv - mean * mean;
    float s = g[t] * rsqrtf(var + 1e-5f);
    sc[t] = s;
    sh[t] = be[t] - mean * s;
  }
  __syncthreads();
  for (int i = blockIdx.x * 256 + t; i < n4; i += gridDim.x * 256) {
    f32x4 x = bf4_to_f32(((const ushort4*)X)[i]);
    int c0 = (i * 4) & (HH - 1);
    ushort4 o;
    o.x = f2bf(fmaxf(x.x * sc[c0 + 0] + sh[c0 + 0], 0.f));
    o.y = f2bf(fmaxf(x.y * sc[c0 + 1] + sh[c0 + 1], 0.f));
    o.z = f2bf(fmaxf(x.z * sc[c0 + 2] + sh[c0 + 2], 0.f));
    o.w = f2bf(fmaxf(x.w * sc[c0 + 3] + sh[c0 + 3], 0.f));
    ((ushort4*)out)[i] = o;
  }
}

// Layer-2 BN apply, packed for the head: out[r] = bf16(relu(BN(X[idx[r]]))).
__global__ __launch_bounds__(256) void k_bnrc_pack(const unsigned short* __restrict__ X,
                                                   const float* __restrict__ sums,
                                                   const float* __restrict__ g,
                                                   const float* __restrict__ be,
                                                   const int* __restrict__ idx,
                                                   unsigned short* __restrict__ out) {
  __shared__ float sc[HH], sh[HH];
  int t = threadIdx.x;
  {
    float inv = 1.f / (float)NN;
    float mean = sums[t] * inv;
    float var = sums[HH + t] * inv - mean * mean;
    float s = g[t] * rsqrtf(var + 1e-5f);
    sc[t] = s;
    sh[t] = be[t] - mean * s;
  }
  __syncthreads();
  int i = blockIdx.x * 256 + t;
  int orow = i >> 6;           // wave-uniform
  int c0 = (i & 63) * 4;
  int irow = idx[orow];
  f32x4 x = bf4_to_f32(*(const ushort4*)(X + (size_t)irow * HH + c0));
  ushort4 o;
  o.x = f2bf(fmaxf(x.x * sc[c0 + 0] + sh[c0 + 0], 0.f));
  o.y = f2bf(fmaxf(x.y * sc[c0 + 1] + sh[c0 + 1], 0.f));
  o.z = f2bf(fmaxf(x.z * sc[c0 + 2] + sh[c0 + 2], 0.f));
  o.w = f2bf(fmaxf(x.w * sc[c0 + 3] + sh[c0 + 3], 0.f));
  ((ushort4*)out)[i] = o;
}

// ---------------- GEMM: C(MxNn) = A(MxK,bf16) * Bt(NnxK,bf16)^T + bias ----------------
// 128x128 tile, BK=64, 3 blocks/CU. OUTB=1: bf16 out; 0: fp32 out.
template <int OUTB>
__global__ __launch_bounds__(256, 3) void k_gemm(const unsigned short* __restrict__ A,
                                                 const unsigned short* __restrict__ Bt,
                                                 const float* __restrict__ bias,
                                                 void* __restrict__ Cv,
                                                 int M, int K, int Nn) {
  __shared__ unsigned short lA[128 * 64];
  __shared__ unsigned short lB[128 * 64];
  const int tid = threadIdx.x;
  const int wave = tid >> 6, lane = tid & 63;
  const int m0 = blockIdx.x * 128, n0 = blockIdx.y * 128;
  const int wm = (wave >> 1) * 64, wn = (wave & 1) * 64;
  const int lhi = lane >> 4, llo = lane & 15;
  const int srow = lane >> 3;
  const int scol = (lane & 7) * 8;
  const unsigned short *pA[4], *pB[4];
#pragma unroll
  for (int j = 0; j < 4; ++j) {
    int base = (wave * 4 + j) * 8 + srow;
    int ar = m0 + base;
    ar = ar < M ? ar : 0;
    pA[j] = A + (size_t)ar * K + scol;
    pB[j] = Bt + (size_t)(n0 + base) * K + scol;
  }
  f32x4 zero = {0.f, 0.f, 0.f, 0.f};
  f32x4 acc[4][4];
#pragma unroll
  for (int i = 0; i < 4; ++i)
#pragma unroll
    for (int j = 0; j < 4; ++j) acc[i][j] = zero;
  for (int k0 = 0; k0 < K; k0 += 64) {
#pragma unroll
    for (int j = 0; j < 4; ++j) {
      gload_lds16(pA[j] + k0, lA + (wave * 4 + j) * 8 * 64);
      gload_lds16(pB[j] + k0, lB + (wave * 4 + j) * 8 * 64);
    }
    __syncthreads();
    bf16x8 af[2][4], bfv[2][4];
#pragma unroll
    for (int ks = 0; ks < 2; ++ks) {
#pragma unroll
      for (int mt = 0; mt < 4; ++mt)
        af[ks][mt] = *(const bf16x8*)(lA + (wm + mt * 16 + llo) * 64 + ks * 32 + lhi * 8);
#pragma unroll
      for (int nt = 0; nt < 4; ++nt)
        bfv[ks][nt] = *(const bf16x8*)(lB + (wn + nt * 16 + llo) * 64 + ks * 32 + lhi * 8);
    }
#pragma unroll
    for (int ks = 0; ks < 2; ++ks)
#pragma unroll
      for (int mt = 0; mt < 4; ++mt)
#pragma unroll
        for (int nt = 0; nt < 4; ++nt)
          acc[mt][nt] = __builtin_amdgcn_mfma_f32_16x16x32_bf16(af[ks][mt], bfv[ks][nt], acc[mt][nt], 0, 0, 0);
    __syncthreads();
  }
#pragma unroll
  for (int nt = 0; nt < 4; ++nt) {
    int cn = n0 + wn + nt * 16 + llo;
    float bv = bias ? bias[cn] : 0.f;
#pragma unroll
    for (int mt = 0; mt < 4; ++mt) {
      int cm0 = m0 + wm + mt * 16 + lhi * 4;
#pragma unroll
      for (int r = 0; r < 4; ++r) {
        int cm = cm0 + r;
        if (cm < M) {
          float v = acc[mt][nt][r] + bv;
          if (OUTB)
            ((unsigned short*)Cv)[(size_t)cm * Nn + cn] = f2bf(v);
          else
            ((float*)Cv)[(size_t)cm * Nn + cn] = v;
        }
      }
    }
  }
}

extern "C" void kernel_launch(void* const* d_in, const int* in_sizes, int n_in,
                              void* d_out, int out_size, void* d_ws, size_t ws_size,
                              hipStream_t stream) {
  const float* features = (const float*)d_in[0];
  const float* edge_vals = (const float*)d_in[1];
  const float* W1 = (const float*)d_in[2];
  const float* db1 = (const float*)d_in[3];
  // d_in[4] = b1  — annihilated by training-mode BN
  const float* g1 = (const float*)d_in[5];
  const float* be1 = (const float*)d_in[6];
  const float* W2 = (const float*)d_in[7];
  // d_in[8] = b2  — annihilated by BN
  const float* g2 = (const float*)d_in[9];
  const float* be2 = (const float*)d_in[10];
  const float* Wf = (const float*)d_in[11];
  const float* bfb = (const float*)d_in[12];
  const int* erows = (const int*)d_in[13];
  const int* ecols = (const int*)d_in[14];
  const int* idx = (const int*)d_in[15];
  const int M3 = in_sizes[15];
  (void)n_in; (void)out_size; (void)ws_size;

  char* ws = (char*)d_ws;
  size_t off = 0;
  auto alloc = [&](size_t bytes) -> void* {
    void* p = (void*)(ws + off);
    off += (bytes + 255) & ~(size_t)255;
    return p;
  };
  unsigned short* Xb = (unsigned short*)alloc((size_t)NN * HH * 2);
  unsigned short* Ab = (unsigned short*)alloc((size_t)NN * HH * 2);
  unsigned short* Yb = (unsigned short*)alloc((size_t)NN * HH * 2);
  unsigned short* Pb = (unsigned short*)alloc((size_t)25000 * HH * 2);
  unsigned short* W1t = (unsigned short*)alloc((size_t)FF * HH * 2);
  unsigned short* W2t = (unsigned short*)alloc((size_t)HH * HH * 2);
  unsigned short* Wft = (unsigned short*)alloc((size_t)HH * LL * 2);
  int* cursor = (int*)alloc((size_t)NN * 4);
  int* cnt = (int*)alloc((size_t)NN * 4);
  unsigned int* csr = (unsigned int*)alloc((size_t)EE * 4);
  float* part = (float*)alloc((size_t)2 * SBLK * 256 * 4);
  float* stats = (float*)alloc(4 * HH * 4 + 256);
  float* sums1 = stats;
  float* sums2 = stats + 2 * HH;
  int* total = (int*)(stats + 4 * HH);

  hipMemsetAsync(cnt, 0, (size_t)NN * 4, stream);
  hipMemsetAsync(stats, 0, 4 * HH * 4 + 256, stream);

  // setup: hist + feature cast + weight transposes (one launch, hist first)
  k_setup<<<15665, 256, 0, stream>>>(erows, cnt, features, Xb, W1, W1t, W2, W2t, Wf, Wft);
  k_alloc<<<(NN + 255) / 256, 256, 0, stream>>>(cnt, cursor, total, NN);

  // layer 1: gemm fused with CSR fill (independent work, co-scheduled)
  k_l1<<<1564, 256, 0, stream>>>(Xb, W1t, db1, Ab, NN, FF, HH,
                                 erows, ecols, edge_vals, cursor, csr, EE);
  // after k_l1: cursor[row] == row end
  k_spmm<<<(NN + 3) / 4, 256, 0, stream>>>(Ab, cursor, cnt, csr, Yb, NN);
  k_bnstats<<<SBLK, 256, 0, stream>>>(Yb, part, NN);
  k_bnred<<<16, 256, 0, stream>>>(part, sums1);
  k_bnrc<<<2048, 256, 0, stream>>>(Yb, sums1, g1, be1, Xb, NN * HH / 4);

  // layer 2
  k_gemm<1><<<dim3((NN + 127) / 128, HH / 128), 256, 0, stream>>>(Xb, W2t, nullptr, Ab, NN, HH, HH);
  k_spmm<<<(NN + 3) / 4, 256, 0, stream>>>(Ab, cursor, cnt, csr, Yb, NN);
  k_bnstats<<<SBLK, 256, 0, stream>>>(Yb, part, NN);
  k_bnred<<<16, 256, 0, stream>>>(part, sums2);
  k_bnrc_pack<<<(M3 * 64) / 256, 256, 0, stream>>>(Yb, sums2, g2, be2, idx, Pb);

  // head: C = Pb @ Wf + bf
  k_gemm<0><<<dim3((M3 + 127) / 128, LL / 128), 256, 0, stream>>>(Pb, Wft, bfb, d_out, M3, HH, LL);
}